// Round 3
// baseline (1741.590 us; speedup 1.0000x reference)
//
#include <hip/hip_runtime.h>
#include <hip/hip_bf16.h>

#define NN 20000
#define KK 16
#define DD 128
#define HH 256
#define IN3 384

typedef __hip_bfloat16 bf16;
typedef __bf16 bf8v __attribute__((ext_vector_type(8)));
typedef float f4v __attribute__((ext_vector_type(4)));

#define MFMA16(a, b, c) __builtin_amdgcn_mfma_f32_16x16x32_bf16((a), (b), (c), 0, 0, 0)

// hs aliases xs cols 128.. (bytes 256..783 of each 784-B row).
// Valid: after GEMM1's k-loop, xs cols 128..383 are dead (gates re-read only
// pair cols 0..127).
#define HS_AT(base, r, c) (*((bf16*)(base) + (size_t)(r) * 392 + 128 + (c)))

// bf16 transposed-weight layout (element offsets):
// Wt1  [512][384] : rows 0-255 Wg1^T, 256-511 Wv1^T
// Wto1 [128][256] : Wo1^T
// Wtg  [256][128] : rows 0-127 Win^T, 128-255 Wout^T
// Wt2  [512][384] : Wg2^T / Wv2^T
// Wto2 [128][256] : Wo2^T
#define WT1_OFS  0
#define WTO1_OFS 196608
#define WTG_OFS  229376
#define WT2_OFS  262144
#define WTO2_OFS 458752
#define WT_TOTAL 491520

__device__ __forceinline__ float gelu_tanh(float x) {
    const float c = 0.7978845608028654f;
    float y = c * (x + 0.044715f * x * x * x);
    float e = __expf(-2.0f * fabsf(y));          // in (0,1], no overflow
    float th = (1.0f - e) / (1.0f + e);          // |tanh|
    th = copysignf(th, y);
    return 0.5f * x * (1.0f + th);
}
__device__ __forceinline__ float sigm(float x) { return 1.0f / (1.0f + __expf(-x)); }

__global__ __launch_bounds__(256) void k_prep(
    const float* __restrict__ Wg1, const float* __restrict__ Wv1,
    const float* __restrict__ Wo1,
    const float* __restrict__ Win, const float* __restrict__ Wout,
    const float* __restrict__ Wg2, const float* __restrict__ Wv2,
    const float* __restrict__ Wo2, bf16* __restrict__ wt)
{
    int idx = blockIdx.x * 256 + threadIdx.x;
    if (idx >= WT_TOTAL) return;
    float v;
    if (idx < WTO1_OFS) {
        int i = idx, n = i / IN3, k = i % IN3;
        v = (n < HH) ? Wg1[(size_t)k * HH + n] : Wv1[(size_t)k * HH + (n - HH)];
    } else if (idx < WTG_OFS) {
        int i = idx - WTO1_OFS, n = i / HH, k = i % HH;
        v = Wo1[(size_t)k * DD + n];
    } else if (idx < WT2_OFS) {
        int i = idx - WTG_OFS, n = i / DD, k = i % DD;
        v = (n < DD) ? Win[(size_t)k * DD + n] : Wout[(size_t)k * DD + (n - DD)];
    } else if (idx < WTO2_OFS) {
        int i = idx - WT2_OFS, n = i / IN3, k = i % IN3;
        v = (n < HH) ? Wg2[(size_t)k * HH + n] : Wv2[(size_t)k * HH + (n - HH)];
    } else {
        int i = idx - WTO2_OFS, n = i / HH, k = i % HH;
        v = Wo2[(size_t)k * DD + n];
    }
    wt[idx] = __float2bfloat16(v);
}

// One block = 4 nodes (M = 64 rows). 5000 blocks. 256 threads = 4 waves.
// LDS ~50.7 KB -> 3 blocks/CU.
// GEMM1: wave w owns 8 ntile pairs (cols), all 4 mtiles (rows).
// Back half: wave w owns node w entirely — GEMM2, LayerNorm (in-register via
// shfl), pu (registers), gates, and all stores are wave-private, barrier-free.
__global__ __launch_bounds__(256) void k_pair(
    const float* __restrict__ localp, const float* __restrict__ pairp,
    const int* __restrict__ nbrs, const float* __restrict__ mask,
    const bf16* __restrict__ wt,
    const float* __restrict__ bg1, const float* __restrict__ bv1,
    const float* __restrict__ bo1,
    const float* __restrict__ gp, const float* __restrict__ bp,
    float* __restrict__ out, float* __restrict__ inc_ws,
    float* __restrict__ outg_ws)
{
    __shared__ bf16 xs[64][392];           // 50176 B (A; cols 128.. alias hs)
    __shared__ int   nbr_s[64];
    __shared__ float msk_s[64];

    const int t = threadIdx.x;
    const int n0 = blockIdx.x * 4;
    const int l = t & 63, w = t >> 6;
    const int lg = l & 15, lq = l >> 4;

    if (t < 64) {
        int node = t >> 4, k = t & 15;
        int nb = nbrs[(n0 + node) * KK + k];
        int nbw = (nb < 0) ? nb + NN : nb;     // JAX negative-index wrap
        nbr_s[t] = nbw;
        msk_s[t] = (nb != -1 && mask[nbw] > 0.0f) ? 1.0f : 0.0f;
    }
    __syncthreads();

    // Stage x rows (f32 -> bf16), packed 8-B LDS writes
    for (int idx = t; idx < 64 * 96; idx += 256) {
        int row = idx / 96, g = idx % 96, c = g * 4;
        int node = row >> 4, k = row & 15;
        float4 v;
        if (c < 128)      v = *(const float4*)&pairp[((size_t)(n0 + node) * KK + k) * DD + c];
        else if (c < 256) v = *(const float4*)&localp[(size_t)(n0 + node) * DD + (c - 128)];
        else              v = *(const float4*)&localp[(size_t)nbr_s[row] * DD + (c - 256)];
        union { ushort4 u4; bf16 b[4]; } pk;
        pk.b[0] = __float2bfloat16(v.x); pk.b[1] = __float2bfloat16(v.y);
        pk.b[2] = __float2bfloat16(v.z); pk.b[3] = __float2bfloat16(v.w);
        *(ushort4*)&xs[row][c] = pk.u4;
    }
    __syncthreads();

    // ---- GEMM1: [64x384] @ Wt1^T -> g|v [64x512] ----
    f4v acc[4][8];
#pragma unroll
    for (int i = 0; i < 4; i++)
#pragma unroll
        for (int j = 0; j < 8; j++) acc[i][j] = (f4v){0.f, 0.f, 0.f, 0.f};

    const bf16* Wt1 = wt + WT1_OFS;
    for (int ko = 0; ko < 12; ko++) {
        bf8v A0 = *(const bf8v*)&xs[     lg][ko * 32 + lq * 8];
        bf8v A1 = *(const bf8v*)&xs[16 + lg][ko * 32 + lq * 8];
        bf8v A2 = *(const bf8v*)&xs[32 + lg][ko * 32 + lq * 8];
        bf8v A3 = *(const bf8v*)&xs[48 + lg][ko * 32 + lq * 8];
#pragma unroll
        for (int ntl = 0; ntl < 8; ntl++) {
            int nrow = (ntl < 4) ? (w * 4 + ntl) * 16 + lg
                                 : 256 + (w * 4 + (ntl - 4)) * 16 + lg;
            bf8v B = *(const bf8v*)(Wt1 + (size_t)nrow * IN3 + ko * 32 + lq * 8);
            acc[0][ntl] = MFMA16(A0, B, acc[0][ntl]);
            acc[1][ntl] = MFMA16(A1, B, acc[1][ntl]);
            acc[2][ntl] = MFMA16(A2, B, acc[2][ntl]);
            acc[3][ntl] = MFMA16(A3, B, acc[3][ntl]);
        }
    }
    __syncthreads();   // GEMM1 xs reads done -> hs (aliased) writable

    // epilogue: h = gelu(g+bg)*(v+bv) -> hs (aliased into xs cols 128..)
#pragma unroll
    for (int ntl = 0; ntl < 4; ntl++) {
        int colg = (w * 4 + ntl) * 16 + lg;
        float bg = bg1[colg], bv = bv1[colg];
#pragma unroll
        for (int mt = 0; mt < 4; mt++)
#pragma unroll
            for (int r = 0; r < 4; r++) {
                float g = acc[mt][ntl][r] + bg;
                float vv = acc[mt][ntl + 4][r] + bv;
                HS_AT(xs, mt * 16 + lq * 4 + r, colg) = __float2bfloat16(gelu_tanh(g) * vv);
            }
    }
    __syncthreads();   // hs complete; no LDS writes after this point

    // ---- GEMM2 (wave-private): h[16x256] @ Wo1 -> u[16x128] for node w ----
    f4v acc2[8];
#pragma unroll
    for (int j = 0; j < 8; j++) acc2[j] = (f4v){0.f, 0.f, 0.f, 0.f};
    const bf16* Wto1 = wt + WTO1_OFS;
    for (int ko = 0; ko < 8; ko++) {
        bf8v A = *(const bf8v*)&HS_AT(xs, w * 16 + lg, ko * 32 + lq * 8);
#pragma unroll
        for (int nt = 0; nt < 8; nt++) {
            bf8v B = *(const bf8v*)(Wto1 + (size_t)(nt * 16 + lg) * HH + ko * 32 + lq * 8);
            acc2[nt] = MFMA16(A, B, acc2[nt]);
        }
    }
    // bias + full LN in-wave: row k = lq*4+r, cols nt*16+lg cover all 128
    float s[4] = {0, 0, 0, 0}, s2[4] = {0, 0, 0, 0};
#pragma unroll
    for (int nt = 0; nt < 8; nt++) {
        float bo = bo1[nt * 16 + lg];
#pragma unroll
        for (int r = 0; r < 4; r++) {
            float u = acc2[nt][r] + bo;
            acc2[nt][r] = u;
            s[r] += u; s2[r] += u * u;
        }
    }
#pragma unroll
    for (int off = 1; off < 16; off <<= 1)
#pragma unroll
        for (int r = 0; r < 4; r++) {
            s[r]  += __shfl_xor(s[r], off, 64);
            s2[r] += __shfl_xor(s2[r], off, 64);
        }
    float mean[4], rstd[4];
#pragma unroll
    for (int r = 0; r < 4; r++) {
        mean[r] = s[r] * (1.0f / DD);
        float var = s2[r] * (1.0f / DD) - mean[r] * mean[r];
        rstd[r] = rsqrtf(var + 1e-5f);
    }

    // pu in registers + pair-output store
    float pu[8][4];
    const size_t OUT_PAIR_OFS = (size_t)NN * DD;
#pragma unroll
    for (int nt = 0; nt < 8; nt++) {
        int col = nt * 16 + lg;
        float gpd = gp[col], bpd = bp[col];
#pragma unroll
        for (int r = 0; r < 4; r++) {
            float p = (acc2[nt][r] - mean[r]) * rstd[r] * gpd + bpd;
            pu[nt][r] = p;
            size_t gidx = ((size_t)(n0 + w) * KK + (lq * 4 + r)) * DD + col;
            out[OUT_PAIR_OFS + gidx] = pairp[gidx] + p;
        }
    }

    // ---- Gates (wave-private): pair[16x128] @ {Win, Wout} for node w ----
    f4v a3i[8], a3o[8];
#pragma unroll
    for (int j = 0; j < 8; j++) {
        a3i[j] = (f4v){0.f, 0.f, 0.f, 0.f};
        a3o[j] = (f4v){0.f, 0.f, 0.f, 0.f};
    }
    const bf16* Wtg = wt + WTG_OFS;
    for (int ko = 0; ko < 4; ko++) {
        bf8v A = *(const bf8v*)&xs[w * 16 + lg][ko * 32 + lq * 8];  // pair cols intact
#pragma unroll
        for (int nt = 0; nt < 8; nt++) {
            bf8v Bi = *(const bf8v*)(Wtg + (size_t)(nt * 16 + lg) * DD + ko * 32 + lq * 8);
            bf8v Bo = *(const bf8v*)(Wtg + (size_t)((8 + nt) * 16 + lg) * DD + ko * 32 + lq * 8);
            a3i[nt] = MFMA16(A, Bi, a3i[nt]);
            a3o[nt] = MFMA16(A, Bo, a3o[nt]);
        }
    }
    float mk[4]; int nb[4];
#pragma unroll
    for (int r = 0; r < 4; r++) {
        mk[r] = msk_s[w * 16 + lq * 4 + r];
        nb[r] = nbr_s[w * 16 + lq * 4 + r];
    }
    // incoming: sum_k sigm(gin)*pu*mask  (reduce over k = lq*4+r)
#pragma unroll
    for (int nt = 0; nt < 8; nt++) {
        float sl = 0.f;
#pragma unroll
        for (int r = 0; r < 4; r++)
            sl += sigm(a3i[nt][r]) * pu[nt][r] * mk[r];
        sl += __shfl_xor(sl, 16, 64);
        sl += __shfl_xor(sl, 32, 64);
        if (l < 16)
            inc_ws[(size_t)(n0 + w) * DD + nt * 16 + l] = sl;
    }
    // outgoing: scatter-add sigm(gout)*pu*mask to neighbour rows
#pragma unroll
    for (int nt = 0; nt < 8; nt++) {
        int col = nt * 16 + lg;
#pragma unroll
        for (int r = 0; r < 4; r++) {
            if (mk[r] != 0.0f) {
                float o = sigm(a3o[nt][r]) * pu[nt][r];
                atomicAdd(&outg_ws[(size_t)nb[r] * DD + col], o);
            }
        }
    }
}

// One block = 16 nodes. 1250 blocks. LDS ~13.1 KB.
__global__ __launch_bounds__(256, 4) void k_local(
    const float* __restrict__ localp, const float* __restrict__ inc_ws,
    const float* __restrict__ outg_ws, const bf16* __restrict__ wt,
    const float* __restrict__ bg2, const float* __restrict__ bv2,
    const float* __restrict__ bo2,
    const float* __restrict__ gl, const float* __restrict__ bl,
    float* __restrict__ out)
{
    __shared__ bf16 xs[16][392];           // cols 128.. alias hs
    __shared__ float lnp[4][16][2];

    const int t = threadIdx.x;
    const int n0 = blockIdx.x * 16;
    const int l = t & 63, w = t >> 6;
    const int lg = l & 15, lq = l >> 4;

    for (int idx = t; idx < 16 * 96; idx += 256) {
        int row = idx / 96, g = idx % 96, c = g * 4;
        size_t node = n0 + row;
        float4 v;
        if (c < 128)      v = *(const float4*)&localp[node * DD + c];
        else if (c < 256) v = *(const float4*)&inc_ws[node * DD + (c - 128)];
        else              v = *(const float4*)&outg_ws[node * DD + (c - 256)];
        union { ushort4 u4; bf16 b[4]; } pk;
        pk.b[0] = __float2bfloat16(v.x); pk.b[1] = __float2bfloat16(v.y);
        pk.b[2] = __float2bfloat16(v.z); pk.b[3] = __float2bfloat16(v.w);
        *(ushort4*)&xs[row][c] = pk.u4;
    }
    __syncthreads();

    // GEMM1: [16x384] @ Wt2^T -> g|v [16x512]; wave w owns 4 g/v tile-pairs
    f4v acc[8];
#pragma unroll
    for (int j = 0; j < 8; j++) acc[j] = (f4v){0.f, 0.f, 0.f, 0.f};
    const bf16* Wt2 = wt + WT2_OFS;
    for (int ko = 0; ko < 12; ko++) {
        bf8v A = *(const bf8v*)&xs[lg][ko * 32 + lq * 8];
#pragma unroll
        for (int ntl = 0; ntl < 8; ntl++) {
            int nrow = (ntl < 4) ? (w * 4 + ntl) * 16 + lg
                                 : 256 + (w * 4 + (ntl - 4)) * 16 + lg;
            bf8v B = *(const bf8v*)(Wt2 + (size_t)nrow * IN3 + ko * 32 + lq * 8);
            acc[ntl] = MFMA16(A, B, acc[ntl]);
        }
    }
    __syncthreads();   // GEMM1 xs reads done -> hs (aliased) writable

#pragma unroll
    for (int ntl = 0; ntl < 4; ntl++) {
        int colg = (w * 4 + ntl) * 16 + lg;
        float bg = bg2[colg], bv = bv2[colg];
#pragma unroll
        for (int r = 0; r < 4; r++) {
            float g = acc[ntl][r] + bg;
            float vv = acc[ntl + 4][r] + bv;
            HS_AT(xs, lq * 4 + r, colg) = __float2bfloat16(gelu_tanh(g) * vv);
        }
    }
    __syncthreads();

    // GEMM2: h[16x256] @ Wo2 -> u[16x128]; wave w owns col-tiles w*2, w*2+1
    f4v acc2[2];
#pragma unroll
    for (int j = 0; j < 2; j++) acc2[j] = (f4v){0.f, 0.f, 0.f, 0.f};
    const bf16* Wto2 = wt + WTO2_OFS;
    for (int ko = 0; ko < 8; ko++) {
        bf8v A = *(const bf8v*)&HS_AT(xs, lg, ko * 32 + lq * 8);
#pragma unroll
        for (int nt = 0; nt < 2; nt++) {
            bf8v B = *(const bf8v*)(Wto2 + (size_t)((w * 2 + nt) * 16 + lg) * HH + ko * 32 + lq * 8);
            acc2[nt] = MFMA16(A, B, acc2[nt]);
        }
    }
    float s[4] = {0, 0, 0, 0}, s2[4] = {0, 0, 0, 0};
#pragma unroll
    for (int nt = 0; nt < 2; nt++) {
        float bo = bo2[(w * 2 + nt) * 16 + lg];
#pragma unroll
        for (int r = 0; r < 4; r++) {
            float u = acc2[nt][r] + bo;
            acc2[nt][r] = u;
            s[r] += u; s2[r] += u * u;
        }
    }
#pragma unroll
    for (int off = 1; off < 16; off <<= 1)
#pragma unroll
        for (int r = 0; r < 4; r++) {
            s[r]  += __shfl_xor(s[r], off, 64);
            s2[r] += __shfl_xor(s2[r], off, 64);
        }
    if (lg == 0)
#pragma unroll
        for (int r = 0; r < 4; r++) {
            lnp[w][lq * 4 + r][0] = s[r];
            lnp[w][lq * 4 + r][1] = s2[r];
        }
    __syncthreads();

#pragma unroll
    for (int nt = 0; nt < 2; nt++) {
        int col = (w * 2 + nt) * 16 + lg;
        float gld = gl[col], bld = bl[col];
#pragma unroll
        for (int r = 0; r < 4; r++) {
            int row = lq * 4 + r;
            float S  = lnp[0][row][0] + lnp[1][row][0] + lnp[2][row][0] + lnp[3][row][0];
            float S2 = lnp[0][row][1] + lnp[1][row][1] + lnp[2][row][1] + lnp[3][row][1];
            float mean = S * (1.0f / DD);
            float var = S2 * (1.0f / DD) - mean * mean;
            float rstd = rsqrtf(var + 1e-5f);
            float p = (acc2[nt][r] - mean) * rstd * gld + bld;
            size_t node = n0 + row;
            out[node * DD + col] = localp[node * DD + col] + p;
        }
    }
}

extern "C" void kernel_launch(void* const* d_in, const int* in_sizes, int n_in,
                              void* d_out, int out_size, void* d_ws, size_t ws_size,
                              hipStream_t stream) {
    const float* local = (const float*)d_in[0];
    const float* pair  = (const float*)d_in[1];
    const int*   nbrs  = (const int*)d_in[2];
    const float* mask  = (const float*)d_in[3];
    const float* Wg1 = (const float*)d_in[4];
    const float* bg1 = (const float*)d_in[5];
    const float* Wv1 = (const float*)d_in[6];
    const float* bv1 = (const float*)d_in[7];
    const float* Wo1 = (const float*)d_in[8];
    const float* bo1 = (const float*)d_in[9];
    const float* gp  = (const float*)d_in[10];
    const float* bp  = (const float*)d_in[11];
    const float* Win = (const float*)d_in[12];
    const float* Wout= (const float*)d_in[13];
    const float* Wg2 = (const float*)d_in[14];
    const float* bg2 = (const float*)d_in[15];
    const float* Wv2 = (const float*)d_in[16];
    const float* bv2 = (const float*)d_in[17];
    const float* Wo2 = (const float*)d_in[18];
    const float* bo2 = (const float*)d_in[19];
    const float* gl  = (const float*)d_in[20];
    const float* bl  = (const float*)d_in[21];

    float* out = (float*)d_out;
    float* inc_ws  = (float*)d_ws;
    float* outg_ws = inc_ws + (size_t)NN * DD;
    bf16*  wt      = (bf16*)(outg_ws + (size_t)NN * DD);

    hipMemsetAsync(outg_ws, 0, (size_t)NN * DD * sizeof(float), stream);
    k_prep<<<(WT_TOTAL + 255) / 256, 256, 0, stream>>>(
        Wg1, Wv1, Wo1, Win, Wout, Wg2, Wv2, Wo2, wt);
    k_pair<<<NN / 4, 256, 0, stream>>>(local, pair, nbrs, mask, wt,
                                       bg1, bv1, bo1, gp, bp,
                                       out, inc_ws, outg_ws);
    k_local<<<NN / 16, 256, 0, stream>>>(local, inc_ws, outg_ws, wt,
                                         bg2, bv2, bo2, gl, bl, out);
}

// Round 4
// 1205.193 us; speedup vs baseline: 1.4451x; 1.4451x over previous
//
#include <hip/hip_runtime.h>
#include <hip/hip_bf16.h>

#define NN 20000
#define KK 16
#define DD 128
#define HH 256
#define IN3 384

typedef __hip_bfloat16 bf16;
typedef __bf16 bf8v __attribute__((ext_vector_type(8)));
typedef float f4v __attribute__((ext_vector_type(4)));

#define MFMA16(a, b, c) __builtin_amdgcn_mfma_f32_16x16x32_bf16((a), (b), (c), 0, 0, 0)

// hs/pu alias xs cols 128.. (bytes 256..783 of each 784-B row):
//   hs[r][c] (bf16, c<264)  == xs[r][128+c]
//   pu[r][c] (f32,  c<132)  == bytes 256+4c of row r
// Valid: after GEMM1's k-loop xs cols 128..383 are dead (gates re-read only
// pair cols 0..127).
#define HS_AT(base, r, c) (*((bf16*)(base) + (size_t)(r) * 392 + 128 + (c)))
#define PU_AT(base, r, c) (*((float*)(base) + (size_t)(r) * 196 + 64 + (c)))

// bf16 transposed-weight layout (element offsets):
// Wt1  [512][384] : rows 0-255 Wg1^T, 256-511 Wv1^T
// Wto1 [128][256] : Wo1^T
// Wtg  [256][128] : rows 0-127 Win^T, 128-255 Wout^T
// Wt2  [512][384] : Wg2^T / Wv2^T
// Wto2 [128][256] : Wo2^T
#define WT1_OFS  0
#define WTO1_OFS 196608
#define WTG_OFS  229376
#define WT2_OFS  262144
#define WTO2_OFS 458752
#define WT_TOTAL 491520

__device__ __forceinline__ float gelu_tanh(float x) {
    const float c = 0.7978845608028654f;
    float y = c * (x + 0.044715f * x * x * x);
    float e = __expf(-2.0f * fabsf(y));          // in (0,1], no overflow
    float th = (1.0f - e) / (1.0f + e);          // |tanh|
    th = copysignf(th, y);
    return 0.5f * x * (1.0f + th);
}
__device__ __forceinline__ float sigm(float x) { return 1.0f / (1.0f + __expf(-x)); }

__global__ __launch_bounds__(256) void k_prep(
    const float* __restrict__ Wg1, const float* __restrict__ Wv1,
    const float* __restrict__ Wo1,
    const float* __restrict__ Win, const float* __restrict__ Wout,
    const float* __restrict__ Wg2, const float* __restrict__ Wv2,
    const float* __restrict__ Wo2, bf16* __restrict__ wt)
{
    int idx = blockIdx.x * 256 + threadIdx.x;
    if (idx >= WT_TOTAL) return;
    float v;
    if (idx < WTO1_OFS) {
        int i = idx, n = i / IN3, k = i % IN3;
        v = (n < HH) ? Wg1[(size_t)k * HH + n] : Wv1[(size_t)k * HH + (n - HH)];
    } else if (idx < WTG_OFS) {
        int i = idx - WTO1_OFS, n = i / HH, k = i % HH;
        v = Wo1[(size_t)k * DD + n];
    } else if (idx < WT2_OFS) {
        int i = idx - WTG_OFS, n = i / DD, k = i % DD;
        v = (n < DD) ? Win[(size_t)k * DD + n] : Wout[(size_t)k * DD + (n - DD)];
    } else if (idx < WTO2_OFS) {
        int i = idx - WT2_OFS, n = i / IN3, k = i % IN3;
        v = (n < HH) ? Wg2[(size_t)k * HH + n] : Wv2[(size_t)k * HH + (n - HH)];
    } else {
        int i = idx - WTO2_OFS, n = i / HH, k = i % HH;
        v = Wo2[(size_t)k * DD + n];
    }
    wt[idx] = __float2bfloat16(v);
}

// One block = 2 nodes (M = 32 rows). 10000 blocks. 256 threads = 4 waves.
// LDS ~25.9 KB. All ko-loops FULLY UNROLLED with precomputed base pointers:
// weight loads become base+imm, compiler hoists them across iterations
// (counted vmcnt instead of per-iteration drain-all) -> cross-iter MLP.
__global__ __launch_bounds__(256, 3) void k_pair(
    const float* __restrict__ localp, const float* __restrict__ pairp,
    const int* __restrict__ nbrs, const float* __restrict__ mask,
    const bf16* __restrict__ wt,
    const float* __restrict__ bg1, const float* __restrict__ bv1,
    const float* __restrict__ bo1,
    const float* __restrict__ gp, const float* __restrict__ bp,
    float* __restrict__ out, float* __restrict__ inc_ws,
    float* __restrict__ outg_ws)
{
    __shared__ bf16 xs[32][392];           // A; cols 128.. alias hs/pu
    __shared__ float lnp[2][32][2];
    __shared__ int   nbr_s[32];
    __shared__ float msk_s[32];

    const int t = threadIdx.x;
    const int n0 = blockIdx.x * 2;
    const int l = t & 63, w = t >> 6;
    const int lg = l & 15, lq = l >> 4;
    const int m = w & 1, nh = w >> 1;

    if (t < 32) {
        int node = t >> 4, k = t & 15;
        int nb = nbrs[(n0 + node) * KK + k];
        int nbw = (nb < 0) ? nb + NN : nb;     // JAX negative-index wrap
        nbr_s[t] = nbw;
        msk_s[t] = (nb != -1 && mask[nbw] > 0.0f) ? 1.0f : 0.0f;
    }
    __syncthreads();

    // Stage x rows (f32 -> bf16), packed 8-B LDS writes, unrolled
#pragma unroll
    for (int it = 0; it < 12; it++) {
        int idx = t + it * 256;
        int row = idx / 96, g = idx % 96, c = g * 4;
        int node = row >> 4, k = row & 15;
        float4 v;
        if (c < 128)      v = *(const float4*)&pairp[((size_t)(n0 + node) * KK + k) * DD + c];
        else if (c < 256) v = *(const float4*)&localp[(size_t)(n0 + node) * DD + (c - 128)];
        else              v = *(const float4*)&localp[(size_t)nbr_s[row] * DD + (c - 256)];
        union { ushort4 u4; bf16 b[4]; } pk;
        pk.b[0] = __float2bfloat16(v.x); pk.b[1] = __float2bfloat16(v.y);
        pk.b[2] = __float2bfloat16(v.z); pk.b[3] = __float2bfloat16(v.w);
        *(ushort4*)&xs[row][c] = pk.u4;
    }
    __syncthreads();

    // ---- GEMM1: [32x384] @ Wt1^T -> g|v [32x512] ----
    f4v acc[2][8];
#pragma unroll
    for (int i = 0; i < 2; i++)
#pragma unroll
        for (int j = 0; j < 8; j++) acc[i][j] = (f4v){0.f, 0.f, 0.f, 0.f};

    // per-ntl B row base pointers (row-major [512][384], lane offset lq*8)
    const bf16* bp1[8];
#pragma unroll
    for (int ntl = 0; ntl < 8; ntl++) {
        int nrow = (ntl < 4) ? (w * 4 + ntl) * 16 + lg
                             : 256 + (w * 4 + (ntl - 4)) * 16 + lg;
        bp1[ntl] = wt + WT1_OFS + (size_t)nrow * IN3 + lq * 8;
    }
#pragma unroll
    for (int ko = 0; ko < 12; ko++) {
        bf8v A0 = *(const bf8v*)&xs[lg][ko * 32 + lq * 8];
        bf8v A1 = *(const bf8v*)&xs[16 + lg][ko * 32 + lq * 8];
#pragma unroll
        for (int ntl = 0; ntl < 8; ntl++) {
            bf8v B = *(const bf8v*)(bp1[ntl] + ko * 32);
            acc[0][ntl] = MFMA16(A0, B, acc[0][ntl]);
            acc[1][ntl] = MFMA16(A1, B, acc[1][ntl]);
        }
    }
    __syncthreads();   // GEMM1 xs reads done -> hs (aliased) writable

    // epilogue: h = gelu(g+bg)*(v+bv) -> hs (aliased into xs cols 128..)
#pragma unroll
    for (int ntl = 0; ntl < 4; ntl++) {
        int colg = (w * 4 + ntl) * 16 + lg;
        float bg = bg1[colg], bv = bv1[colg];
#pragma unroll
        for (int mt = 0; mt < 2; mt++)
#pragma unroll
            for (int r = 0; r < 4; r++) {
                float g = acc[mt][ntl][r] + bg;
                float vv = acc[mt][ntl + 4][r] + bv;
                HS_AT(xs, mt * 16 + lq * 4 + r, colg) = __float2bfloat16(gelu_tanh(g) * vv);
            }
    }
    __syncthreads();

    // ---- GEMM2: h[32x256] @ Wo1 -> u; wave (m, nh): node m, col-tiles nh*4.. ----
    f4v acc2[4];
#pragma unroll
    for (int j = 0; j < 4; j++) acc2[j] = (f4v){0.f, 0.f, 0.f, 0.f};
    const bf16* bp2[4];
#pragma unroll
    for (int nt = 0; nt < 4; nt++)
        bp2[nt] = wt + WTO1_OFS + (size_t)((nh * 4 + nt) * 16 + lg) * HH + lq * 8;
#pragma unroll
    for (int ko = 0; ko < 8; ko++) {
        bf8v A = *(const bf8v*)&HS_AT(xs, m * 16 + lg, ko * 32 + lq * 8);
#pragma unroll
        for (int nt = 0; nt < 4; nt++) {
            bf8v B = *(const bf8v*)(bp2[nt] + ko * 32);
            acc2[nt] = MFMA16(A, B, acc2[nt]);
        }
    }
    // bias + LN partial over this wave's 64 cols
    float s[4] = {0, 0, 0, 0}, s2[4] = {0, 0, 0, 0};
#pragma unroll
    for (int nt = 0; nt < 4; nt++) {
        float bo = bo1[(nh * 4 + nt) * 16 + lg];
#pragma unroll
        for (int r = 0; r < 4; r++) {
            float u = acc2[nt][r] + bo;
            acc2[nt][r] = u;
            s[r] += u; s2[r] += u * u;
        }
    }
#pragma unroll
    for (int off = 1; off < 16; off <<= 1)
#pragma unroll
        for (int r = 0; r < 4; r++) {
            s[r]  += __shfl_xor(s[r], off, 64);
            s2[r] += __shfl_xor(s2[r], off, 64);
        }
    if (lg == 0)
#pragma unroll
        for (int r = 0; r < 4; r++) {
            lnp[nh][m * 16 + lq * 4 + r][0] = s[r];
            lnp[nh][m * 16 + lq * 4 + r][1] = s2[r];
        }
    __syncthreads();   // partials ready; all hs reads done -> pu may overwrite

    float mean[4], rstd[4];
#pragma unroll
    for (int r = 0; r < 4; r++) {
        int row = m * 16 + lq * 4 + r;
        float S  = lnp[0][row][0] + lnp[1][row][0];
        float S2 = lnp[0][row][1] + lnp[1][row][1];
        mean[r] = S * (1.0f / DD);
        float var = S2 * (1.0f / DD) - mean[r] * mean[r];
        rstd[r] = rsqrtf(var + 1e-5f);
    }

    const size_t OUT_PAIR_OFS = (size_t)NN * DD;
#pragma unroll
    for (int nt = 0; nt < 4; nt++) {
        int col = (nh * 4 + nt) * 16 + lg;
        float gpd = gp[col], bpd = bp[col];
#pragma unroll
        for (int r = 0; r < 4; r++) {
            int row = m * 16 + lq * 4 + r;
            float p = (acc2[nt][r] - mean[r]) * rstd[r] * gpd + bpd;
            PU_AT(xs, row, col) = p;
            size_t gidx = ((size_t)(n0 + m) * KK + (lq * 4 + r)) * DD + col;
            out[OUT_PAIR_OFS + gidx] = pairp[gidx] + p;
        }
    }
    __syncthreads();   // pu visible to gate waves

    // ---- Gates: pair[16x128] @ Win (nh=0) or Wout (nh=1) for node m ----
    f4v acc3[8];
#pragma unroll
    for (int j = 0; j < 8; j++) acc3[j] = (f4v){0.f, 0.f, 0.f, 0.f};
    const bf16* bp3[8];
#pragma unroll
    for (int nt = 0; nt < 8; nt++)
        bp3[nt] = wt + WTG_OFS + (size_t)((nh * 8 + nt) * 16 + lg) * DD + lq * 8;
#pragma unroll
    for (int ko = 0; ko < 4; ko++) {
        bf8v A = *(const bf8v*)&xs[m * 16 + lg][ko * 32 + lq * 8];  // pair cols intact
#pragma unroll
        for (int nt = 0; nt < 8; nt++) {
            bf8v B = *(const bf8v*)(bp3[nt] + ko * 32);
            acc3[nt] = MFMA16(A, B, acc3[nt]);
        }
    }
    if (nh == 0) {
        // incoming: sum_k sigm(gin)*pu*mask  (coalesced store)
#pragma unroll
        for (int nt = 0; nt < 8; nt++) {
            int col = nt * 16 + lg;
            float sl = 0.f;
#pragma unroll
            for (int r = 0; r < 4; r++) {
                int k = lq * 4 + r;
                sl += sigm(acc3[nt][r]) * PU_AT(xs, m * 16 + k, col) * msk_s[m * 16 + k];
            }
            sl += __shfl_xor(sl, 16, 64);
            sl += __shfl_xor(sl, 32, 64);
            if (l < 16)
                inc_ws[(size_t)(n0 + m) * DD + nt * 16 + l] = sl;
        }
    } else {
        // outgoing: scatter-add sigm(gout)*pu*mask to neighbour rows
        // (proven cost-equivalent to streaming og + gather in R2)
#pragma unroll
        for (int nt = 0; nt < 8; nt++) {
            int col = nt * 16 + lg;
#pragma unroll
            for (int r = 0; r < 4; r++) {
                int k = lq * 4 + r;
                if (msk_s[m * 16 + k] != 0.0f) {
                    float o = sigm(acc3[nt][r]) * PU_AT(xs, m * 16 + k, col);
                    atomicAdd(&outg_ws[(size_t)nbr_s[m * 16 + k] * DD + col], o);
                }
            }
        }
    }
}

// One block = 16 nodes. 1250 blocks. LDS ~13.1 KB. Same unroll treatment.
__global__ __launch_bounds__(256, 4) void k_local(
    const float* __restrict__ localp, const float* __restrict__ inc_ws,
    const float* __restrict__ outg_ws, const bf16* __restrict__ wt,
    const float* __restrict__ bg2, const float* __restrict__ bv2,
    const float* __restrict__ bo2,
    const float* __restrict__ gl, const float* __restrict__ bl,
    float* __restrict__ out)
{
    __shared__ bf16 xs[16][392];           // cols 128.. alias hs
    __shared__ float lnp[4][16][2];

    const int t = threadIdx.x;
    const int n0 = blockIdx.x * 16;
    const int l = t & 63, w = t >> 6;
    const int lg = l & 15, lq = l >> 4;

#pragma unroll
    for (int it = 0; it < 6; it++) {
        int idx = t + it * 256;
        int row = idx / 96, g = idx % 96, c = g * 4;
        size_t node = n0 + row;
        float4 v;
        if (c < 128)      v = *(const float4*)&localp[node * DD + c];
        else if (c < 256) v = *(const float4*)&inc_ws[node * DD + (c - 128)];
        else              v = *(const float4*)&outg_ws[node * DD + (c - 256)];
        union { ushort4 u4; bf16 b[4]; } pk;
        pk.b[0] = __float2bfloat16(v.x); pk.b[1] = __float2bfloat16(v.y);
        pk.b[2] = __float2bfloat16(v.z); pk.b[3] = __float2bfloat16(v.w);
        *(ushort4*)&xs[row][c] = pk.u4;
    }
    __syncthreads();

    // GEMM1: [16x384] @ Wt2^T -> g|v [16x512]; wave w owns 4 g/v tile-pairs
    f4v acc[8];
#pragma unroll
    for (int j = 0; j < 8; j++) acc[j] = (f4v){0.f, 0.f, 0.f, 0.f};
    const bf16* bpl1[8];
#pragma unroll
    for (int ntl = 0; ntl < 8; ntl++) {
        int nrow = (ntl < 4) ? (w * 4 + ntl) * 16 + lg
                             : 256 + (w * 4 + (ntl - 4)) * 16 + lg;
        bpl1[ntl] = wt + WT2_OFS + (size_t)nrow * IN3 + lq * 8;
    }
#pragma unroll
    for (int ko = 0; ko < 12; ko++) {
        bf8v A = *(const bf8v*)&xs[lg][ko * 32 + lq * 8];
#pragma unroll
        for (int ntl = 0; ntl < 8; ntl++) {
            bf8v B = *(const bf8v*)(bpl1[ntl] + ko * 32);
            acc[ntl] = MFMA16(A, B, acc[ntl]);
        }
    }
    __syncthreads();   // GEMM1 xs reads done -> hs (aliased) writable

#pragma unroll
    for (int ntl = 0; ntl < 4; ntl++) {
        int colg = (w * 4 + ntl) * 16 + lg;
        float bg = bg2[colg], bv = bv2[colg];
#pragma unroll
        for (int r = 0; r < 4; r++) {
            float g = acc[ntl][r] + bg;
            float vv = acc[ntl + 4][r] + bv;
            HS_AT(xs, lq * 4 + r, colg) = __float2bfloat16(gelu_tanh(g) * vv);
        }
    }
    __syncthreads();

    // GEMM2: h[16x256] @ Wo2 -> u[16x128]; wave w owns col-tiles w*2, w*2+1
    f4v acc2[2];
#pragma unroll
    for (int j = 0; j < 2; j++) acc2[j] = (f4v){0.f, 0.f, 0.f, 0.f};
    const bf16* bpl2[2];
#pragma unroll
    for (int nt = 0; nt < 2; nt++)
        bpl2[nt] = wt + WTO2_OFS + (size_t)((w * 2 + nt) * 16 + lg) * HH + lq * 8;
#pragma unroll
    for (int ko = 0; ko < 8; ko++) {
        bf8v A = *(const bf8v*)&HS_AT(xs, lg, ko * 32 + lq * 8);
#pragma unroll
        for (int nt = 0; nt < 2; nt++) {
            bf8v B = *(const bf8v*)(bpl2[nt] + ko * 32);
            acc2[nt] = MFMA16(A, B, acc2[nt]);
        }
    }
    float s[4] = {0, 0, 0, 0}, s2[4] = {0, 0, 0, 0};
#pragma unroll
    for (int nt = 0; nt < 2; nt++) {
        float bo = bo2[(w * 2 + nt) * 16 + lg];
#pragma unroll
        for (int r = 0; r < 4; r++) {
            float u = acc2[nt][r] + bo;
            acc2[nt][r] = u;
            s[r] += u; s2[r] += u * u;
        }
    }
#pragma unroll
    for (int off = 1; off < 16; off <<= 1)
#pragma unroll
        for (int r = 0; r < 4; r++) {
            s[r]  += __shfl_xor(s[r], off, 64);
            s2[r] += __shfl_xor(s2[r], off, 64);
        }
    if (lg == 0)
#pragma unroll
        for (int r = 0; r < 4; r++) {
            lnp[w][lq * 4 + r][0] = s[r];
            lnp[w][lq * 4 + r][1] = s2[r];
        }
    __syncthreads();

#pragma unroll
    for (int nt = 0; nt < 2; nt++) {
        int col = (w * 2 + nt) * 16 + lg;
        float gld = gl[col], bld = bl[col];
#pragma unroll
        for (int r = 0; r < 4; r++) {
            int row = lq * 4 + r;
            float S  = lnp[0][row][0] + lnp[1][row][0] + lnp[2][row][0] + lnp[3][row][0];
            float S2 = lnp[0][row][1] + lnp[1][row][1] + lnp[2][row][1] + lnp[3][row][1];
            float mean = S * (1.0f / DD);
            float var = S2 * (1.0f / DD) - mean * mean;
            float rstd = rsqrtf(var + 1e-5f);
            float p = (acc2[nt][r] - mean) * rstd * gld + bld;
            size_t node = n0 + row;
            out[node * DD + col] = localp[node * DD + col] + p;
        }
    }
}

extern "C" void kernel_launch(void* const* d_in, const int* in_sizes, int n_in,
                              void* d_out, int out_size, void* d_ws, size_t ws_size,
                              hipStream_t stream) {
    const float* local = (const float*)d_in[0];
    const float* pair  = (const float*)d_in[1];
    const int*   nbrs  = (const int*)d_in[2];
    const float* mask  = (const float*)d_in[3];
    const float* Wg1 = (const float*)d_in[4];
    const float* bg1 = (const float*)d_in[5];
    const float* Wv1 = (const float*)d_in[6];
    const float* bv1 = (const float*)d_in[7];
    const float* Wo1 = (const float*)d_in[8];
    const float* bo1 = (const float*)d_in[9];
    const float* gp  = (const float*)d_in[10];
    const float* bp  = (const float*)d_in[11];
    const float* Win = (const float*)d_in[12];
    const float* Wout= (const float*)d_in[13];
    const float* Wg2 = (const float*)d_in[14];
    const float* bg2 = (const float*)d_in[15];
    const float* Wv2 = (const float*)d_in[16];
    const float* bv2 = (const float*)d_in[17];
    const float* Wo2 = (const float*)d_in[18];
    const float* bo2 = (const float*)d_in[19];
    const float* gl  = (const float*)d_in[20];
    const float* bl  = (const float*)d_in[21];

    float* out = (float*)d_out;
    float* inc_ws  = (float*)d_ws;
    float* outg_ws = inc_ws + (size_t)NN * DD;
    bf16*  wt      = (bf16*)(outg_ws + (size_t)NN * DD);

    hipMemsetAsync(outg_ws, 0, (size_t)NN * DD * sizeof(float), stream);
    k_prep<<<(WT_TOTAL + 255) / 256, 256, 0, stream>>>(
        Wg1, Wv1, Wo1, Win, Wout, Wg2, Wv2, Wo2, wt);
    k_pair<<<NN / 2, 256, 0, stream>>>(local, pair, nbrs, mask, wt,
                                       bg1, bv1, bo1, gp, bp,
                                       out, inc_ws, outg_ws);
    k_local<<<NN / 16, 256, 0, stream>>>(local, inc_ws, outg_ws, wt,
                                         bg2, bv2, bo2, gl, bl, out);
}

// Round 5
// 1199.384 us; speedup vs baseline: 1.4521x; 1.0048x over previous
//
#include <hip/hip_runtime.h>
#include <hip/hip_bf16.h>

#define NN 20000
#define KK 16
#define DD 128
#define HH 256
#define IN3 384

typedef __hip_bfloat16 bf16;
typedef __bf16 bf8v __attribute__((ext_vector_type(8)));
typedef float f4v __attribute__((ext_vector_type(4)));

#define MFMA16(a, b, c) __builtin_amdgcn_mfma_f32_16x16x32_bf16((a), (b), (c), 0, 0, 0)

// hs/pu alias xs cols 128.. (bytes 256..783 of each 784-B row):
//   hs[r][c] (bf16, c<264)  == xs[r][128+c]
//   pu[r][c] (f32,  c<132)  == bytes 256+4c of row r
// Valid: after GEMM1's k-loop xs cols 128..383 are dead (gates re-read only
// pair cols 0..127).
#define HS_AT(base, r, c) (*((bf16*)(base) + (size_t)(r) * 392 + 128 + (c)))
#define PU_AT(base, r, c) (*((float*)(base) + (size_t)(r) * 196 + 64 + (c)))

// bf16 transposed-weight layout (element offsets):
// Wt1  [512][384] : rows 0-255 Wg1^T, 256-511 Wv1^T
// Wto1 [128][256] : Wo1^T
// Wtg  [256][128] : rows 0-127 Win^T, 128-255 Wout^T
// Wt2  [512][384] : Wg2^T / Wv2^T
// Wto2 [128][256] : Wo2^T
#define WT1_OFS  0
#define WTO1_OFS 196608
#define WTG_OFS  229376
#define WT2_OFS  262144
#define WTO2_OFS 458752
#define WT_TOTAL 491520

__device__ __forceinline__ float gelu_tanh(float x) {
    const float c = 0.7978845608028654f;
    float y = c * (x + 0.044715f * x * x * x);
    float e = __expf(-2.0f * fabsf(y));          // in (0,1], no overflow
    float th = (1.0f - e) / (1.0f + e);          // |tanh|
    th = copysignf(th, y);
    return 0.5f * x * (1.0f + th);
}
__device__ __forceinline__ float sigm(float x) { return 1.0f / (1.0f + __expf(-x)); }

__global__ __launch_bounds__(256) void k_prep(
    const float* __restrict__ Wg1, const float* __restrict__ Wv1,
    const float* __restrict__ Wo1,
    const float* __restrict__ Win, const float* __restrict__ Wout,
    const float* __restrict__ Wg2, const float* __restrict__ Wv2,
    const float* __restrict__ Wo2, bf16* __restrict__ wt)
{
    int idx = blockIdx.x * 256 + threadIdx.x;
    if (idx >= WT_TOTAL) return;
    float v;
    if (idx < WTO1_OFS) {
        int i = idx, n = i / IN3, k = i % IN3;
        v = (n < HH) ? Wg1[(size_t)k * HH + n] : Wv1[(size_t)k * HH + (n - HH)];
    } else if (idx < WTG_OFS) {
        int i = idx - WTO1_OFS, n = i / HH, k = i % HH;
        v = Wo1[(size_t)k * DD + n];
    } else if (idx < WT2_OFS) {
        int i = idx - WTG_OFS, n = i / DD, k = i % DD;
        v = (n < DD) ? Win[(size_t)k * DD + n] : Wout[(size_t)k * DD + (n - DD)];
    } else if (idx < WTO2_OFS) {
        int i = idx - WT2_OFS, n = i / IN3, k = i % IN3;
        v = (n < HH) ? Wg2[(size_t)k * HH + n] : Wv2[(size_t)k * HH + (n - HH)];
    } else {
        int i = idx - WTO2_OFS, n = i / HH, k = i % HH;
        v = Wo2[(size_t)k * DD + n];
    }
    wt[idx] = __float2bfloat16(v);
}

// One block = 2 nodes (M = 32 rows). 10000 blocks. 512 threads = 8 THIN waves.
// Per-wave: GEMM1 acc[2][4] (32 AGPR), 48 weight loads (was 64 AGPR / 96 loads
// at 4 waves). Target <=85 regs/wave -> 6 waves/SIMD (24/CU) for 2x MLP.
// GEMM1: wave w owns ntile pairs (g:(w*2+i)*16, v:256+(w*2+i)*16), i<2.
// GEMM2: wave (m=w&1, nq=w>>1): node m, col-quarter nq (32 cols).
// Gates: wave (m=w&1, g2=(w>>1)&1, h2=w>>2): node m, Win/Wout, col-half h2.
__global__ __launch_bounds__(512, 6) void k_pair(
    const float* __restrict__ localp, const float* __restrict__ pairp,
    const int* __restrict__ nbrs, const float* __restrict__ mask,
    const bf16* __restrict__ wt,
    const float* __restrict__ bg1, const float* __restrict__ bv1,
    const float* __restrict__ bo1,
    const float* __restrict__ gp, const float* __restrict__ bp,
    float* __restrict__ out, float* __restrict__ inc_ws,
    float* __restrict__ outg_ws)
{
    __shared__ bf16 xs[32][392];           // A; cols 128.. alias hs/pu
    __shared__ float lnp[4][32][2];        // LN partials per col-quarter
    __shared__ int   nbr_s[32];
    __shared__ float msk_s[32];

    const int t = threadIdx.x;
    const int n0 = blockIdx.x * 2;
    const int l = t & 63, w = t >> 6;
    const int lg = l & 15, lq = l >> 4;
    const int m = w & 1;

    if (t < 32) {
        int node = t >> 4, k = t & 15;
        int nb = nbrs[(n0 + node) * KK + k];
        int nbw = (nb < 0) ? nb + NN : nb;     // JAX negative-index wrap
        nbr_s[t] = nbw;
        msk_s[t] = (nb != -1 && mask[nbw] > 0.0f) ? 1.0f : 0.0f;
    }
    __syncthreads();

    // Stage x rows (f32 -> bf16), packed 8-B LDS writes
#pragma unroll
    for (int it = 0; it < 6; it++) {
        int idx = t + it * 512;
        int row = idx / 96, g = idx % 96, c = g * 4;
        int node = row >> 4, k = row & 15;
        float4 v;
        if (c < 128)      v = *(const float4*)&pairp[((size_t)(n0 + node) * KK + k) * DD + c];
        else if (c < 256) v = *(const float4*)&localp[(size_t)(n0 + node) * DD + (c - 128)];
        else              v = *(const float4*)&localp[(size_t)nbr_s[row] * DD + (c - 256)];
        union { ushort4 u4; bf16 b[4]; } pk;
        pk.b[0] = __float2bfloat16(v.x); pk.b[1] = __float2bfloat16(v.y);
        pk.b[2] = __float2bfloat16(v.z); pk.b[3] = __float2bfloat16(v.w);
        *(ushort4*)&xs[row][c] = pk.u4;
    }
    __syncthreads();

    // ---- GEMM1: [32x384] @ Wt1^T -> g|v [32x512], 2 tile-pairs per wave ----
    f4v acc[2][4];
#pragma unroll
    for (int i = 0; i < 2; i++)
#pragma unroll
        for (int j = 0; j < 4; j++) acc[i][j] = (f4v){0.f, 0.f, 0.f, 0.f};

    const bf16* bp1[4];
#pragma unroll
    for (int j = 0; j < 4; j++) {
        int nrow = (j < 2) ? (w * 2 + j) * 16 + lg
                           : 256 + (w * 2 + (j - 2)) * 16 + lg;
        bp1[j] = wt + WT1_OFS + (size_t)nrow * IN3 + lq * 8;
    }
#pragma unroll
    for (int ko = 0; ko < 12; ko++) {
        bf8v A0 = *(const bf8v*)&xs[lg][ko * 32 + lq * 8];
        bf8v A1 = *(const bf8v*)&xs[16 + lg][ko * 32 + lq * 8];
#pragma unroll
        for (int j = 0; j < 4; j++) {
            bf8v B = *(const bf8v*)(bp1[j] + ko * 32);
            acc[0][j] = MFMA16(A0, B, acc[0][j]);
            acc[1][j] = MFMA16(A1, B, acc[1][j]);
        }
    }
    __syncthreads();   // GEMM1 xs reads done -> hs (aliased) writable

    // epilogue: h = gelu(g+bg)*(v+bv) -> hs (aliased into xs cols 128..)
#pragma unroll
    for (int ntl = 0; ntl < 2; ntl++) {
        int colg = (w * 2 + ntl) * 16 + lg;
        float bg = bg1[colg], bv = bv1[colg];
#pragma unroll
        for (int mt = 0; mt < 2; mt++)
#pragma unroll
            for (int r = 0; r < 4; r++) {
                float g = acc[mt][ntl][r] + bg;
                float vv = acc[mt][ntl + 2][r] + bv;
                HS_AT(xs, mt * 16 + lq * 4 + r, colg) = __float2bfloat16(gelu_tanh(g) * vv);
            }
    }
    __syncthreads();

    // ---- GEMM2: h[32x256] @ Wo1 -> u; wave (m, nq): node m, col-quarter ----
    const int nq = w >> 1;
    f4v acc2[2];
#pragma unroll
    for (int j = 0; j < 2; j++) acc2[j] = (f4v){0.f, 0.f, 0.f, 0.f};
    const bf16* bp2[2];
#pragma unroll
    for (int nt = 0; nt < 2; nt++)
        bp2[nt] = wt + WTO1_OFS + (size_t)((nq * 2 + nt) * 16 + lg) * HH + lq * 8;
#pragma unroll
    for (int ko = 0; ko < 8; ko++) {
        bf8v A = *(const bf8v*)&HS_AT(xs, m * 16 + lg, ko * 32 + lq * 8);
#pragma unroll
        for (int nt = 0; nt < 2; nt++) {
            bf8v B = *(const bf8v*)(bp2[nt] + ko * 32);
            acc2[nt] = MFMA16(A, B, acc2[nt]);
        }
    }
    // bias + LN partial over this wave's 32 cols
    float s[4] = {0, 0, 0, 0}, s2[4] = {0, 0, 0, 0};
#pragma unroll
    for (int nt = 0; nt < 2; nt++) {
        float bo = bo1[(nq * 2 + nt) * 16 + lg];
#pragma unroll
        for (int r = 0; r < 4; r++) {
            float u = acc2[nt][r] + bo;
            acc2[nt][r] = u;
            s[r] += u; s2[r] += u * u;
        }
    }
#pragma unroll
    for (int off = 1; off < 16; off <<= 1)
#pragma unroll
        for (int r = 0; r < 4; r++) {
            s[r]  += __shfl_xor(s[r], off, 64);
            s2[r] += __shfl_xor(s2[r], off, 64);
        }
    if (lg == 0)
#pragma unroll
        for (int r = 0; r < 4; r++) {
            lnp[nq][m * 16 + lq * 4 + r][0] = s[r];
            lnp[nq][m * 16 + lq * 4 + r][1] = s2[r];
        }
    __syncthreads();   // partials ready; all hs reads done -> pu may overwrite

    float mean[4], rstd[4];
#pragma unroll
    for (int r = 0; r < 4; r++) {
        int row = m * 16 + lq * 4 + r;
        float S  = lnp[0][row][0] + lnp[1][row][0] + lnp[2][row][0] + lnp[3][row][0];
        float S2 = lnp[0][row][1] + lnp[1][row][1] + lnp[2][row][1] + lnp[3][row][1];
        mean[r] = S * (1.0f / DD);
        float var = S2 * (1.0f / DD) - mean[r] * mean[r];
        rstd[r] = rsqrtf(var + 1e-5f);
    }

    const size_t OUT_PAIR_OFS = (size_t)NN * DD;
#pragma unroll
    for (int nt = 0; nt < 2; nt++) {
        int col = (nq * 2 + nt) * 16 + lg;
        float gpd = gp[col], bpd = bp[col];
#pragma unroll
        for (int r = 0; r < 4; r++) {
            int row = m * 16 + lq * 4 + r;
            float p = (acc2[nt][r] - mean[r]) * rstd[r] * gpd + bpd;
            PU_AT(xs, row, col) = p;
            size_t gidx = ((size_t)(n0 + m) * KK + (lq * 4 + r)) * DD + col;
            out[OUT_PAIR_OFS + gidx] = pairp[gidx] + p;
        }
    }
    __syncthreads();   // pu visible to gate waves

    // ---- Gates: pair[16x128] @ Win (g2=0) / Wout (g2=1), col-half h2 ----
    const int g2 = (w >> 1) & 1, h2 = w >> 2;
    f4v acc3[4];
#pragma unroll
    for (int j = 0; j < 4; j++) acc3[j] = (f4v){0.f, 0.f, 0.f, 0.f};
    const bf16* bp3[4];
#pragma unroll
    for (int nt = 0; nt < 4; nt++)
        bp3[nt] = wt + WTG_OFS + (size_t)(g2 * 128 + h2 * 64 + nt * 16 + lg) * DD + lq * 8;
#pragma unroll
    for (int ko = 0; ko < 4; ko++) {
        bf8v A = *(const bf8v*)&xs[m * 16 + lg][ko * 32 + lq * 8];  // pair cols intact
#pragma unroll
        for (int nt = 0; nt < 4; nt++) {
            bf8v B = *(const bf8v*)(bp3[nt] + ko * 32);
            acc3[nt] = MFMA16(A, B, acc3[nt]);
        }
    }
    if (g2 == 0) {
        // incoming: sum_k sigm(gin)*pu*mask  (coalesced store)
#pragma unroll
        for (int nt = 0; nt < 4; nt++) {
            int col = h2 * 64 + nt * 16 + lg;
            float sl = 0.f;
#pragma unroll
            for (int r = 0; r < 4; r++) {
                int k = lq * 4 + r;
                sl += sigm(acc3[nt][r]) * PU_AT(xs, m * 16 + k, col) * msk_s[m * 16 + k];
            }
            sl += __shfl_xor(sl, 16, 64);
            sl += __shfl_xor(sl, 32, 64);
            if (l < 16)
                inc_ws[(size_t)(n0 + m) * DD + h2 * 64 + nt * 16 + l] = sl;
        }
    } else {
        // outgoing: scatter-add sigm(gout)*pu*mask to neighbour rows
        // (atomics proven cost-equivalent to streaming og + gather in R2)
#pragma unroll
        for (int nt = 0; nt < 4; nt++) {
            int col = h2 * 64 + nt * 16 + lg;
#pragma unroll
            for (int r = 0; r < 4; r++) {
                int k = lq * 4 + r;
                if (msk_s[m * 16 + k] != 0.0f) {
                    float o = sigm(acc3[nt][r]) * PU_AT(xs, m * 16 + k, col);
                    atomicAdd(&outg_ws[(size_t)nbr_s[m * 16 + k] * DD + col], o);
                }
            }
        }
    }
}

// One block = 16 nodes. 1250 blocks. 512 threads = 8 thin waves.
// GEMM1: wave w owns 2 g/v tile-pairs (acc[4], 16 AGPR, 48 loads).
// GEMM2: wave w owns col-tile w (acc2[1]).
__global__ __launch_bounds__(512, 6) void k_local(
    const float* __restrict__ localp, const float* __restrict__ inc_ws,
    const float* __restrict__ outg_ws, const bf16* __restrict__ wt,
    const float* __restrict__ bg2, const float* __restrict__ bv2,
    const float* __restrict__ bo2,
    const float* __restrict__ gl, const float* __restrict__ bl,
    float* __restrict__ out)
{
    __shared__ bf16 xs[16][392];           // cols 128.. alias hs
    __shared__ float lnp[8][16][2];

    const int t = threadIdx.x;
    const int n0 = blockIdx.x * 16;
    const int l = t & 63, w = t >> 6;
    const int lg = l & 15, lq = l >> 4;

#pragma unroll
    for (int it = 0; it < 3; it++) {
        int idx = t + it * 512;
        int row = idx / 96, g = idx % 96, c = g * 4;
        size_t node = n0 + row;
        float4 v;
        if (c < 128)      v = *(const float4*)&localp[node * DD + c];
        else if (c < 256) v = *(const float4*)&inc_ws[node * DD + (c - 128)];
        else              v = *(const float4*)&outg_ws[node * DD + (c - 256)];
        union { ushort4 u4; bf16 b[4]; } pk;
        pk.b[0] = __float2bfloat16(v.x); pk.b[1] = __float2bfloat16(v.y);
        pk.b[2] = __float2bfloat16(v.z); pk.b[3] = __float2bfloat16(v.w);
        *(ushort4*)&xs[row][c] = pk.u4;
    }
    __syncthreads();

    // GEMM1: [16x384] @ Wt2^T -> g|v [16x512]; wave w owns 2 g/v tile-pairs
    f4v acc[4];
#pragma unroll
    for (int j = 0; j < 4; j++) acc[j] = (f4v){0.f, 0.f, 0.f, 0.f};
    const bf16* bpl1[4];
#pragma unroll
    for (int j = 0; j < 4; j++) {
        int nrow = (j < 2) ? (w * 2 + j) * 16 + lg
                           : 256 + (w * 2 + (j - 2)) * 16 + lg;
        bpl1[j] = wt + WT2_OFS + (size_t)nrow * IN3 + lq * 8;
    }
#pragma unroll
    for (int ko = 0; ko < 12; ko++) {
        bf8v A = *(const bf8v*)&xs[lg][ko * 32 + lq * 8];
#pragma unroll
        for (int j = 0; j < 4; j++) {
            bf8v B = *(const bf8v*)(bpl1[j] + ko * 32);
            acc[j] = MFMA16(A, B, acc[j]);
        }
    }
    __syncthreads();   // GEMM1 xs reads done -> hs (aliased) writable

#pragma unroll
    for (int ntl = 0; ntl < 2; ntl++) {
        int colg = (w * 2 + ntl) * 16 + lg;
        float bg = bg2[colg], bv = bv2[colg];
#pragma unroll
        for (int r = 0; r < 4; r++) {
            float g = acc[ntl][r] + bg;
            float vv = acc[ntl + 2][r] + bv;
            HS_AT(xs, lq * 4 + r, colg) = __float2bfloat16(gelu_tanh(g) * vv);
        }
    }
    __syncthreads();

    // GEMM2: h[16x256] @ Wo2 -> u[16x128]; wave w owns col-tile w
    f4v acc2 = (f4v){0.f, 0.f, 0.f, 0.f};
    const bf16* bpl2 = wt + WTO2_OFS + (size_t)(w * 16 + lg) * HH + lq * 8;
#pragma unroll
    for (int ko = 0; ko < 8; ko++) {
        bf8v A = *(const bf8v*)&HS_AT(xs, lg, ko * 32 + lq * 8);
        bf8v B = *(const bf8v*)(bpl2 + ko * 32);
        acc2 = MFMA16(A, B, acc2);
    }
    float s[4] = {0, 0, 0, 0}, s2[4] = {0, 0, 0, 0};
    {
        float bo = bo2[w * 16 + lg];
#pragma unroll
        for (int r = 0; r < 4; r++) {
            float u = acc2[r] + bo;
            acc2[r] = u;
            s[r] += u; s2[r] += u * u;
        }
    }
#pragma unroll
    for (int off = 1; off < 16; off <<= 1)
#pragma unroll
        for (int r = 0; r < 4; r++) {
            s[r]  += __shfl_xor(s[r], off, 64);
            s2[r] += __shfl_xor(s2[r], off, 64);
        }
    if (lg == 0)
#pragma unroll
        for (int r = 0; r < 4; r++) {
            lnp[w][lq * 4 + r][0] = s[r];
            lnp[w][lq * 4 + r][1] = s2[r];
        }
    __syncthreads();

    {
        int col = w * 16 + lg;
        float gld = gl[col], bld = bl[col];
#pragma unroll
        for (int r = 0; r < 4; r++) {
            int row = lq * 4 + r;
            float S = 0.f, S2 = 0.f;
#pragma unroll
            for (int q = 0; q < 8; q++) { S += lnp[q][row][0]; S2 += lnp[q][row][1]; }
            float mean = S * (1.0f / DD);
            float var = S2 * (1.0f / DD) - mean * mean;
            float rstd = rsqrtf(var + 1e-5f);
            float p = (acc2[r] - mean) * rstd * gld + bld;
            size_t node = n0 + row;
            out[node * DD + col] = localp[node * DD + col] + p;
        }
    }
}

extern "C" void kernel_launch(void* const* d_in, const int* in_sizes, int n_in,
                              void* d_out, int out_size, void* d_ws, size_t ws_size,
                              hipStream_t stream) {
    const float* local = (const float*)d_in[0];
    const float* pair  = (const float*)d_in[1];
    const int*   nbrs  = (const int*)d_in[2];
    const float* mask  = (const float*)d_in[3];
    const float* Wg1 = (const float*)d_in[4];
    const float* bg1 = (const float*)d_in[5];
    const float* Wv1 = (const float*)d_in[6];
    const float* bv1 = (const float*)d_in[7];
    const float* Wo1 = (const float*)d_in[8];
    const float* bo1 = (const float*)d_in[9];
    const float* gp  = (const float*)d_in[10];
    const float* bp  = (const float*)d_in[11];
    const float* Win = (const float*)d_in[12];
    const float* Wout= (const float*)d_in[13];
    const float* Wg2 = (const float*)d_in[14];
    const float* bg2 = (const float*)d_in[15];
    const float* Wv2 = (const float*)d_in[16];
    const float* bv2 = (const float*)d_in[17];
    const float* Wo2 = (const float*)d_in[18];
    const float* bo2 = (const float*)d_in[19];
    const float* gl  = (const float*)d_in[20];
    const float* bl  = (const float*)d_in[21];

    float* out = (float*)d_out;
    float* inc_ws  = (float*)d_ws;
    float* outg_ws = inc_ws + (size_t)NN * DD;
    bf16*  wt      = (bf16*)(outg_ws + (size_t)NN * DD);

    hipMemsetAsync(outg_ws, 0, (size_t)NN * DD * sizeof(float), stream);
    k_prep<<<(WT_TOTAL + 255) / 256, 256, 0, stream>>>(
        Wg1, Wv1, Wo1, Win, Wout, Wg2, Wv2, Wo2, wt);
    k_pair<<<NN / 2, 512, 0, stream>>>(local, pair, nbrs, mask, wt,
                                       bg1, bv1, bo1, gp, bp,
                                       out, inc_ws, outg_ws);
    k_local<<<NN / 16, 512, 0, stream>>>(local, inc_ws, outg_ws, wt,
                                         bg2, bv2, bo2, gl, bl, out);
}

// Round 6
// 787.415 us; speedup vs baseline: 2.2118x; 1.5232x over previous
//
#include <hip/hip_runtime.h>
#include <hip/hip_bf16.h>

#define NN 20000
#define KK 16
#define DD 128
#define HH 256
#define IN3 384

typedef __hip_bfloat16 bf16;
typedef __bf16 bf8v __attribute__((ext_vector_type(8)));
typedef float f4v __attribute__((ext_vector_type(4)));

#define MFMA16(a, b, c) __builtin_amdgcn_mfma_f32_16x16x32_bf16((a), (b), (c), 0, 0, 0)

// hs/pu alias xs cols 128.. (bytes 256..783 of each 784-B row):
//   hs[r][c] (bf16, c<264)  == xs[r][128+c]
//   pu[r][c] (f32,  c<132)  == bytes 256+4c of row r
#define HS_AT(base, r, c) (*((bf16*)(base) + (size_t)(r) * 392 + 128 + (c)))
#define PU_AT(base, r, c) (*((float*)(base) + (size_t)(r) * 196 + 64 + (c)))

// FRAGMENT-MAJOR weight layout (element offsets). For each 16-col tile T and
// K-step K, a contiguous 512-element (1 KB) block in exact MFMA lane order:
//   frag[(T*NKO + K)*512 + l*8 + e] = W^T[T*16 + (l&15)][K*32 + (l>>4)*8 + e]
// A wave's B-load is base + l*16B -> ONE fully-coalesced contiguous 1KB fetch
// (8 lines, fully consumed, sequential) vs the old row-strided 16-line scatter.
// Wt1  : 32 tiles x 12 ko (g tiles 0-15, v tiles 16-31)
// Wto1 :  8 tiles x  8 ko
// Wtg  : 16 tiles x  4 ko (Win tiles 0-7, Wout tiles 8-15)
// Wt2  : 32 tiles x 12 ko
// Wto2 :  8 tiles x  8 ko
#define WT1_OFS  0
#define WTO1_OFS 196608
#define WTG_OFS  229376
#define WT2_OFS  262144
#define WTO2_OFS 458752
#define WT_TOTAL 491520

__device__ __forceinline__ float gelu_tanh(float x) {
    const float c = 0.7978845608028654f;
    float y = c * (x + 0.044715f * x * x * x);
    float e = __expf(-2.0f * fabsf(y));          // in (0,1], no overflow
    float th = (1.0f - e) / (1.0f + e);          // |tanh|
    th = copysignf(th, y);
    return 0.5f * x * (1.0f + th);
}
__device__ __forceinline__ float sigm(float x) { return 1.0f / (1.0f + __expf(-x)); }

// n-major sweep: consecutive threads read consecutive source columns
// (coalesced f32 reads); 2-B writes scatter across fragment blocks (1 MB
// total, absorbed by L2 write-combining).
__global__ __launch_bounds__(256) void k_prep(
    const float* __restrict__ Wg1, const float* __restrict__ Wv1,
    const float* __restrict__ Wo1,
    const float* __restrict__ Win, const float* __restrict__ Wout,
    const float* __restrict__ Wg2, const float* __restrict__ Wv2,
    const float* __restrict__ Wo2, bf16* __restrict__ wt)
{
    int idx = blockIdx.x * 256 + threadIdx.x;
    if (idx >= WT_TOTAL) return;
    float v; size_t dst;
    if (idx < WTO1_OFS) {                       // Wt1: 384 k-rows x 512 n-cols
        int f = idx, k = f >> 9, n = f & 511;
        int K = k >> 5, lq = (k >> 3) & 3, e = k & 7;
        int T = n >> 4, lg = n & 15;
        dst = WT1_OFS + (size_t)((T * 12 + K) << 9) + ((lq * 16 + lg) << 3) + e;
        v = (n < 256) ? Wg1[(size_t)k * HH + n] : Wv1[(size_t)k * HH + (n - 256)];
    } else if (idx < WTG_OFS) {                 // Wto1: 256 k x 128 n
        int f = idx - WTO1_OFS, k = f >> 7, n = f & 127;
        int K = k >> 5, lq = (k >> 3) & 3, e = k & 7;
        int T = n >> 4, lg = n & 15;
        dst = WTO1_OFS + (size_t)((T * 8 + K) << 9) + ((lq * 16 + lg) << 3) + e;
        v = Wo1[(size_t)k * DD + n];
    } else if (idx < WT2_OFS) {                 // Wtg: 128 k x 256 n (Win|Wout)
        int f = idx - WTG_OFS, k = f >> 8, n = f & 255;
        int K = k >> 5, lq = (k >> 3) & 3, e = k & 7;
        int T = n >> 4, lg = n & 15;
        dst = WTG_OFS + (size_t)((T * 4 + K) << 9) + ((lq * 16 + lg) << 3) + e;
        v = (n < 128) ? Win[(size_t)k * DD + n] : Wout[(size_t)k * DD + (n - 128)];
    } else if (idx < WTO2_OFS) {                // Wt2
        int f = idx - WT2_OFS, k = f >> 9, n = f & 511;
        int K = k >> 5, lq = (k >> 3) & 3, e = k & 7;
        int T = n >> 4, lg = n & 15;
        dst = WT2_OFS + (size_t)((T * 12 + K) << 9) + ((lq * 16 + lg) << 3) + e;
        v = (n < 256) ? Wg2[(size_t)k * HH + n] : Wv2[(size_t)k * HH + (n - 256)];
    } else {                                    // Wto2
        int f = idx - WTO2_OFS, k = f >> 7, n = f & 127;
        int K = k >> 5, lq = (k >> 3) & 3, e = k & 7;
        int T = n >> 4, lg = n & 15;
        dst = WTO2_OFS + (size_t)((T * 8 + K) << 9) + ((lq * 16 + lg) << 3) + e;
        v = Wo2[(size_t)k * DD + n];
    }
    wt[dst] = __float2bfloat16(v);
}

// One block = 2 nodes (M = 32 rows). 10000 blocks. 512 threads = 8 thin waves.
// Identical geometry to R5; ONLY the weight loads changed to fragment-major
// contiguous 1KB fetches.
__global__ __launch_bounds__(512, 6) void k_pair(
    const float* __restrict__ localp, const float* __restrict__ pairp,
    const int* __restrict__ nbrs, const float* __restrict__ mask,
    const bf16* __restrict__ wt,
    const float* __restrict__ bg1, const float* __restrict__ bv1,
    const float* __restrict__ bo1,
    const float* __restrict__ gp, const float* __restrict__ bp,
    float* __restrict__ out, float* __restrict__ inc_ws,
    float* __restrict__ outg_ws)
{
    __shared__ bf16 xs[32][392];           // A; cols 128.. alias hs/pu
    __shared__ float lnp[4][32][2];        // LN partials per col-quarter
    __shared__ int   nbr_s[32];
    __shared__ float msk_s[32];

    const int t = threadIdx.x;
    const int n0 = blockIdx.x * 2;
    const int l = t & 63, w = t >> 6;
    const int lg = l & 15, lq = l >> 4;
    const int m = w & 1;

    if (t < 32) {
        int node = t >> 4, k = t & 15;
        int nb = nbrs[(n0 + node) * KK + k];
        int nbw = (nb < 0) ? nb + NN : nb;     // JAX negative-index wrap
        nbr_s[t] = nbw;
        msk_s[t] = (nb != -1 && mask[nbw] > 0.0f) ? 1.0f : 0.0f;
    }
    __syncthreads();

    // Stage x rows (f32 -> bf16), packed 8-B LDS writes
#pragma unroll
    for (int it = 0; it < 6; it++) {
        int idx = t + it * 512;
        int row = idx / 96, g = idx % 96, c = g * 4;
        int node = row >> 4, k = row & 15;
        float4 v;
        if (c < 128)      v = *(const float4*)&pairp[((size_t)(n0 + node) * KK + k) * DD + c];
        else if (c < 256) v = *(const float4*)&localp[(size_t)(n0 + node) * DD + (c - 128)];
        else              v = *(const float4*)&localp[(size_t)nbr_s[row] * DD + (c - 256)];
        union { ushort4 u4; bf16 b[4]; } pk;
        pk.b[0] = __float2bfloat16(v.x); pk.b[1] = __float2bfloat16(v.y);
        pk.b[2] = __float2bfloat16(v.z); pk.b[3] = __float2bfloat16(v.w);
        *(ushort4*)&xs[row][c] = pk.u4;
    }
    __syncthreads();

    // ---- GEMM1: [32x384] @ Wt1 frags -> g|v [32x512], 2 tile-pairs/wave ----
    f4v acc[2][4];
#pragma unroll
    for (int i = 0; i < 2; i++)
#pragma unroll
        for (int j = 0; j < 4; j++) acc[i][j] = (f4v){0.f, 0.f, 0.f, 0.f};

    const bf16* wl = wt + l * 8;           // lane offset once; bases are uniform
    const bf16* bp1[4];
#pragma unroll
    for (int j = 0; j < 4; j++) {
        int T = (j < 2) ? (w * 2 + j) : 16 + (w * 2 + (j - 2));
        bp1[j] = wl + WT1_OFS + (size_t)(T * 12) * 512;
    }
#pragma unroll
    for (int ko = 0; ko < 12; ko++) {
        bf8v A0 = *(const bf8v*)&xs[lg][ko * 32 + lq * 8];
        bf8v A1 = *(const bf8v*)&xs[16 + lg][ko * 32 + lq * 8];
#pragma unroll
        for (int j = 0; j < 4; j++) {
            bf8v B = *(const bf8v*)(bp1[j] + ko * 512);
            acc[0][j] = MFMA16(A0, B, acc[0][j]);
            acc[1][j] = MFMA16(A1, B, acc[1][j]);
        }
    }
    __syncthreads();   // GEMM1 xs reads done -> hs (aliased) writable

    // epilogue: h = gelu(g+bg)*(v+bv) -> hs (aliased into xs cols 128..)
#pragma unroll
    for (int ntl = 0; ntl < 2; ntl++) {
        int colg = (w * 2 + ntl) * 16 + lg;
        float bg = bg1[colg], bv = bv1[colg];
#pragma unroll
        for (int mt = 0; mt < 2; mt++)
#pragma unroll
            for (int r = 0; r < 4; r++) {
                float g = acc[mt][ntl][r] + bg;
                float vv = acc[mt][ntl + 2][r] + bv;
                HS_AT(xs, mt * 16 + lq * 4 + r, colg) = __float2bfloat16(gelu_tanh(g) * vv);
            }
    }
    __syncthreads();

    // ---- GEMM2: h[32x256] @ Wo1 -> u; wave (m, nq): node m, col-quarter ----
    const int nq = w >> 1;
    f4v acc2[2];
#pragma unroll
    for (int j = 0; j < 2; j++) acc2[j] = (f4v){0.f, 0.f, 0.f, 0.f};
    const bf16* bp2[2];
#pragma unroll
    for (int nt = 0; nt < 2; nt++)
        bp2[nt] = wl + WTO1_OFS + (size_t)((nq * 2 + nt) * 8) * 512;
#pragma unroll
    for (int ko = 0; ko < 8; ko++) {
        bf8v A = *(const bf8v*)&HS_AT(xs, m * 16 + lg, ko * 32 + lq * 8);
#pragma unroll
        for (int nt = 0; nt < 2; nt++) {
            bf8v B = *(const bf8v*)(bp2[nt] + ko * 512);
            acc2[nt] = MFMA16(A, B, acc2[nt]);
        }
    }
    // bias + LN partial over this wave's 32 cols
    float s[4] = {0, 0, 0, 0}, s2[4] = {0, 0, 0, 0};
#pragma unroll
    for (int nt = 0; nt < 2; nt++) {
        float bo = bo1[(nq * 2 + nt) * 16 + lg];
#pragma unroll
        for (int r = 0; r < 4; r++) {
            float u = acc2[nt][r] + bo;
            acc2[nt][r] = u;
            s[r] += u; s2[r] += u * u;
        }
    }
#pragma unroll
    for (int off = 1; off < 16; off <<= 1)
#pragma unroll
        for (int r = 0; r < 4; r++) {
            s[r]  += __shfl_xor(s[r], off, 64);
            s2[r] += __shfl_xor(s2[r], off, 64);
        }
    if (lg == 0)
#pragma unroll
        for (int r = 0; r < 4; r++) {
            lnp[nq][m * 16 + lq * 4 + r][0] = s[r];
            lnp[nq][m * 16 + lq * 4 + r][1] = s2[r];
        }
    __syncthreads();   // partials ready; all hs reads done -> pu may overwrite

    float mean[4], rstd[4];
#pragma unroll
    for (int r = 0; r < 4; r++) {
        int row = m * 16 + lq * 4 + r;
        float S  = lnp[0][row][0] + lnp[1][row][0] + lnp[2][row][0] + lnp[3][row][0];
        float S2 = lnp[0][row][1] + lnp[1][row][1] + lnp[2][row][1] + lnp[3][row][1];
        mean[r] = S * (1.0f / DD);
        float var = S2 * (1.0f / DD) - mean[r] * mean[r];
        rstd[r] = rsqrtf(var + 1e-5f);
    }

    const size_t OUT_PAIR_OFS = (size_t)NN * DD;
#pragma unroll
    for (int nt = 0; nt < 2; nt++) {
        int col = (nq * 2 + nt) * 16 + lg;
        float gpd = gp[col], bpd = bp[col];
#pragma unroll
        for (int r = 0; r < 4; r++) {
            int row = m * 16 + lq * 4 + r;
            float p = (acc2[nt][r] - mean[r]) * rstd[r] * gpd + bpd;
            PU_AT(xs, row, col) = p;
            size_t gidx = ((size_t)(n0 + m) * KK + (lq * 4 + r)) * DD + col;
            out[OUT_PAIR_OFS + gidx] = pairp[gidx] + p;
        }
    }
    __syncthreads();   // pu visible to gate waves

    // ---- Gates: pair[16x128] @ Win (g2=0) / Wout (g2=1), col-half h2 ----
    const int g2 = (w >> 1) & 1, h2 = w >> 2;
    f4v acc3[4];
#pragma unroll
    for (int j = 0; j < 4; j++) acc3[j] = (f4v){0.f, 0.f, 0.f, 0.f};
    const bf16* bp3[4];
#pragma unroll
    for (int nt = 0; nt < 4; nt++)
        bp3[nt] = wl + WTG_OFS + (size_t)((g2 * 8 + h2 * 4 + nt) * 4) * 512;
#pragma unroll
    for (int ko = 0; ko < 4; ko++) {
        bf8v A = *(const bf8v*)&xs[m * 16 + lg][ko * 32 + lq * 8];  // pair cols intact
#pragma unroll
        for (int nt = 0; nt < 4; nt++) {
            bf8v B = *(const bf8v*)(bp3[nt] + ko * 512);
            acc3[nt] = MFMA16(A, B, acc3[nt]);
        }
    }
    if (g2 == 0) {
        // incoming: sum_k sigm(gin)*pu*mask  (coalesced store)
#pragma unroll
        for (int nt = 0; nt < 4; nt++) {
            int col = h2 * 64 + nt * 16 + lg;
            float sl = 0.f;
#pragma unroll
            for (int r = 0; r < 4; r++) {
                int k = lq * 4 + r;
                sl += sigm(acc3[nt][r]) * PU_AT(xs, m * 16 + k, col) * msk_s[m * 16 + k];
            }
            sl += __shfl_xor(sl, 16, 64);
            sl += __shfl_xor(sl, 32, 64);
            if (l < 16)
                inc_ws[(size_t)(n0 + m) * DD + h2 * 64 + nt * 16 + l] = sl;
        }
    } else {
        // outgoing: scatter-add sigm(gout)*pu*mask to neighbour rows
        // (atomics proven cost-equivalent to streaming og + gather in R2)
#pragma unroll
        for (int nt = 0; nt < 4; nt++) {
            int col = h2 * 64 + nt * 16 + lg;
#pragma unroll
            for (int r = 0; r < 4; r++) {
                int k = lq * 4 + r;
                if (msk_s[m * 16 + k] != 0.0f) {
                    float o = sigm(acc3[nt][r]) * PU_AT(xs, m * 16 + k, col);
                    atomicAdd(&outg_ws[(size_t)nbr_s[m * 16 + k] * DD + col], o);
                }
            }
        }
    }
}

// One block = 16 nodes. 1250 blocks. 512 threads = 8 thin waves.
__global__ __launch_bounds__(512, 6) void k_local(
    const float* __restrict__ localp, const float* __restrict__ inc_ws,
    const float* __restrict__ outg_ws, const bf16* __restrict__ wt,
    const float* __restrict__ bg2, const float* __restrict__ bv2,
    const float* __restrict__ bo2,
    const float* __restrict__ gl, const float* __restrict__ bl,
    float* __restrict__ out)
{
    __shared__ bf16 xs[16][392];           // cols 128.. alias hs
    __shared__ float lnp[8][16][2];

    const int t = threadIdx.x;
    const int n0 = blockIdx.x * 16;
    const int l = t & 63, w = t >> 6;
    const int lg = l & 15, lq = l >> 4;

#pragma unroll
    for (int it = 0; it < 3; it++) {
        int idx = t + it * 512;
        int row = idx / 96, g = idx % 96, c = g * 4;
        size_t node = n0 + row;
        float4 v;
        if (c < 128)      v = *(const float4*)&localp[node * DD + c];
        else if (c < 256) v = *(const float4*)&inc_ws[node * DD + (c - 128)];
        else              v = *(const float4*)&outg_ws[node * DD + (c - 256)];
        union { ushort4 u4; bf16 b[4]; } pk;
        pk.b[0] = __float2bfloat16(v.x); pk.b[1] = __float2bfloat16(v.y);
        pk.b[2] = __float2bfloat16(v.z); pk.b[3] = __float2bfloat16(v.w);
        *(ushort4*)&xs[row][c] = pk.u4;
    }
    __syncthreads();

    // GEMM1: [16x384] @ Wt2 frags -> g|v [16x512]; wave w owns 2 tile-pairs
    f4v acc[4];
#pragma unroll
    for (int j = 0; j < 4; j++) acc[j] = (f4v){0.f, 0.f, 0.f, 0.f};
    const bf16* wl = wt + l * 8;
    const bf16* bpl1[4];
#pragma unroll
    for (int j = 0; j < 4; j++) {
        int T = (j < 2) ? (w * 2 + j) : 16 + (w * 2 + (j - 2));
        bpl1[j] = wl + WT2_OFS + (size_t)(T * 12) * 512;
    }
#pragma unroll
    for (int ko = 0; ko < 12; ko++) {
        bf8v A = *(const bf8v*)&xs[lg][ko * 32 + lq * 8];
#pragma unroll
        for (int j = 0; j < 4; j++) {
            bf8v B = *(const bf8v*)(bpl1[j] + ko * 512);
            acc[j] = MFMA16(A, B, acc[j]);
        }
    }
    __syncthreads();   // GEMM1 xs reads done -> hs (aliased) writable

#pragma unroll
    for (int ntl = 0; ntl < 2; ntl++) {
        int colg = (w * 2 + ntl) * 16 + lg;
        float bg = bg2[colg], bv = bv2[colg];
#pragma unroll
        for (int r = 0; r < 4; r++) {
            float g = acc[ntl][r] + bg;
            float vv = acc[ntl + 2][r] + bv;
            HS_AT(xs, lq * 4 + r, colg) = __float2bfloat16(gelu_tanh(g) * vv);
        }
    }
    __syncthreads();

    // GEMM2: h[16x256] @ Wo2 -> u[16x128]; wave w owns col-tile w
    f4v acc2 = (f4v){0.f, 0.f, 0.f, 0.f};
    const bf16* bpl2 = wl + WTO2_OFS + (size_t)(w * 8) * 512;
#pragma unroll
    for (int ko = 0; ko < 8; ko++) {
        bf8v A = *(const bf8v*)&HS_AT(xs, lg, ko * 32 + lq * 8);
        bf8v B = *(const bf8v*)(bpl2 + ko * 512);
        acc2 = MFMA16(A, B, acc2);
    }
    float s[4] = {0, 0, 0, 0}, s2[4] = {0, 0, 0, 0};
    {
        float bo = bo2[w * 16 + lg];
#pragma unroll
        for (int r = 0; r < 4; r++) {
            float u = acc2[r] + bo;
            acc2[r] = u;
            s[r] += u; s2[r] += u * u;
        }
    }
#pragma unroll
    for (int off = 1; off < 16; off <<= 1)
#pragma unroll
        for (int r = 0; r < 4; r++) {
            s[r]  += __shfl_xor(s[r], off, 64);
            s2[r] += __shfl_xor(s2[r], off, 64);
        }
    if (lg == 0)
#pragma unroll
        for (int r = 0; r < 4; r++) {
            lnp[w][lq * 4 + r][0] = s[r];
            lnp[w][lq * 4 + r][1] = s2[r];
        }
    __syncthreads();

    {
        int col = w * 16 + lg;
        float gld = gl[col], bld = bl[col];
#pragma unroll
        for (int r = 0; r < 4; r++) {
            int row = lq * 4 + r;
            float S = 0.f, S2 = 0.f;
#pragma unroll
            for (int q = 0; q < 8; q++) { S += lnp[q][row][0]; S2 += lnp[q][row][1]; }
            float mean = S * (1.0f / DD);
            float var = S2 * (1.0f / DD) - mean * mean;
            float rstd = rsqrtf(var + 1e-5f);
            float p = (acc2[r] - mean) * rstd * gld + bld;
            size_t node = n0 + row;
            out[node * DD + col] = localp[node * DD + col] + p;
        }
    }
}

extern "C" void kernel_launch(void* const* d_in, const int* in_sizes, int n_in,
                              void* d_out, int out_size, void* d_ws, size_t ws_size,
                              hipStream_t stream) {
    const float* local = (const float*)d_in[0];
    const float* pair  = (const float*)d_in[1];
    const int*   nbrs  = (const int*)d_in[2];
    const float* mask  = (const float*)d_in[3];
    const float* Wg1 = (const float*)d_in[4];
    const float* bg1 = (const float*)d_in[5];
    const float* Wv1 = (const float*)d_in[6];
    const float* bv1 = (const float*)d_in[7];
    const float* Wo1 = (const float*)d_in[8];
    const float* bo1 = (const float*)d_in[9];
    const float* gp  = (const float*)d_in[10];
    const float* bp  = (const float*)d_in[11];
    const float* Win = (const float*)d_in[12];
    const float* Wout= (const float*)d_in[13];
    const float* Wg2 = (const float*)d_in[14];
    const float* bg2 = (const float*)d_in[15];
    const float* Wv2 = (const float*)d_in[16];
    const float* bv2 = (const float*)d_in[17];
    const float* Wo2 = (const float*)d_in[18];
    const float* bo2 = (const float*)d_in[19];
    const float* gl  = (const float*)d_in[20];
    const float* bl  = (const float*)d_in[21];

    float* out = (float*)d_out;
    float* inc_ws  = (float*)d_ws;
    float* outg_ws = inc_ws + (size_t)NN * DD;
    bf16*  wt      = (bf16*)(outg_ws + (size_t)NN * DD);

    hipMemsetAsync(outg_ws, 0, (size_t)NN * DD * sizeof(float), stream);
    k_prep<<<(WT_TOTAL + 255) / 256, 256, 0, stream>>>(
        Wg1, Wv1, Wo1, Win, Wout, Wg2, Wv2, Wo2, wt);
    k_pair<<<NN / 2, 512, 0, stream>>>(local, pair, nbrs, mask, wt,
                                       bg1, bv1, bo1, gp, bp,
                                       out, inc_ws, outg_ws);
    k_local<<<NN / 16, 512, 0, stream>>>(local, inc_ws, outg_ws, wt,
                                         bg2, bv2, bo2, gl, bl, out);
}